// Round 3
// baseline (624.676 us; speedup 1.0000x reference)
//
#include <hip/hip_runtime.h>
#include <stdint.h>

typedef unsigned short u16;
typedef __bf16 bf16x8 __attribute__((ext_vector_type(8)));
typedef float f32x4 __attribute__((ext_vector_type(4)));

#define DEV static __device__ __forceinline__

DEV u16 f2b(float f) {                       // f32 -> bf16 RNE
    unsigned u = __float_as_uint(f);
    u += 0x7FFF + ((u >> 16) & 1);
    return (u16)(u >> 16);
}
DEV float b2f(u16 h) { return __uint_as_float((unsigned)h << 16); }

DEV void load16(const void* g, void* l) {    // async global->LDS, 16B/lane
    __builtin_amdgcn_global_load_lds((const __attribute__((address_space(1))) void*)g,
                                     (__attribute__((address_space(3))) void*)l, 16, 0, 0);
}

// ---------------- weight f32 -> bf16 ----------------
__global__ __launch_bounds__(256) void cvt_bf16(const float* __restrict__ src,
                                                u16* __restrict__ dst, int n) {
    int i = (blockIdx.x * 256 + threadIdx.x) * 4;
    if (i < n) {
        float4 f = *(const float4*)(src + i);
        ushort4 o;
        o.x = f2b(f.x); o.y = f2b(f.y); o.z = f2b(f.z); o.w = f2b(f.w);
        *(ushort4*)(dst + i) = o;
    }
}

// ---------------- fused LayerNorm + time-shift mix ----------------
// One block per (b,t) row of the chunk. LN(row t) and LN(row t-1) recomputed,
// then xk/xv/xr = h*mix + hh*(1-mix), written bf16.
template <int NOUT>
__global__ __launch_bounds__(256) void ln_mix(
    const float* __restrict__ x, const float* __restrict__ g, const float* __restrict__ be,
    const float* __restrict__ mk, const float* __restrict__ mv, const float* __restrict__ mr,
    u16* __restrict__ ok, u16* __restrict__ ov, u16* __restrict__ orr, int T) {
    const int C = 512;
    int row = blockIdx.x;
    int t = row % T;
    int tid = threadIdx.x;
    int c = tid * 2;
    const float* xt = x + (size_t)row * C;
    float2 vt = *(const float2*)(xt + c);
    float2 vp = make_float2(0.f, 0.f);
    if (t > 0) vp = *(const float2*)(xt - C + c);

    float s0 = vt.x + vt.y, s1 = vt.x * vt.x + vt.y * vt.y;
    float s2 = vp.x + vp.y, s3 = vp.x * vp.x + vp.y * vp.y;
#pragma unroll
    for (int off = 32; off; off >>= 1) {
        s0 += __shfl_down(s0, off); s1 += __shfl_down(s1, off);
        s2 += __shfl_down(s2, off); s3 += __shfl_down(s3, off);
    }
    __shared__ float sm[16];
    int w = tid >> 6;
    if ((tid & 63) == 0) { sm[w*4+0] = s0; sm[w*4+1] = s1; sm[w*4+2] = s2; sm[w*4+3] = s3; }
    __syncthreads();
    s0 = sm[0] + sm[4] + sm[8]  + sm[12];
    s1 = sm[1] + sm[5] + sm[9]  + sm[13];
    s2 = sm[2] + sm[6] + sm[10] + sm[14];
    s3 = sm[3] + sm[7] + sm[11] + sm[15];

    const float rC = 1.f / 512.f;
    float mu_t = s0 * rC, var_t = s1 * rC - mu_t * mu_t;
    float mu_p = s2 * rC, var_p = s3 * rC - mu_p * mu_p;
    float rs_t = rsqrtf(var_t + 1e-5f);
    float rs_p = rsqrtf(var_p + 1e-5f);

    float xk0[2], xv0[2], xr0[2];
#pragma unroll
    for (int j = 0; j < 2; ++j) {
        int cc = c + j;
        float gg = g[cc], bb = be[cc];
        float xv_ = (j ? vt.y : vt.x);
        float xp_ = (j ? vp.y : vp.x);
        float h  = (xv_ - mu_t) * rs_t * gg + bb;
        float hh = (t > 0) ? ((xp_ - mu_p) * rs_p * gg + bb) : 0.f;
        float a = mk[cc];
        xk0[j] = h * a + hh * (1.f - a);
        if (NOUT == 3) { float av = mv[cc]; xv0[j] = h * av + hh * (1.f - av); }
        float ar = mr[cc];
        xr0[j] = h * ar + hh * (1.f - ar);
    }
    size_t idx = (size_t)row * C + c;
    *(ushort2*)&ok[idx] = make_ushort2(f2b(xk0[0]), f2b(xk0[1]));
    if (NOUT == 3) *(ushort2*)&ov[idx] = make_ushort2(f2b(xv0[0]), f2b(xv0[1]));
    *(ushort2*)&orr[idx] = make_ushort2(f2b(xr0[0]), f2b(xr0[1]));
}

// ---------------- NT GEMM: out[n,d] = sum_c A[n,c]*B[d,c] ----------------
// A: [N][K] bf16, B: [D][K] bf16. 128x128 tile, BK=32, 4 waves of 64x64.
// EPI: 0 bf16 raw | 1 bf16 sigmoid | 2 f32 v+Add | 3 bf16 relu^2 | 4 f32 Add+sig(v)*Mul
template <int EPI>
__global__ __launch_bounds__(256) void gemm_nt(
    const u16* __restrict__ A, const u16* __restrict__ B, void* __restrict__ Out,
    const float* __restrict__ Add, const u16* __restrict__ Mul, int K, int D) {
    const int BM = 128, BN = 128, BK = 32;
    __shared__ __align__(16) u16 As[BM * BK];
    __shared__ __align__(16) u16 Bs[BN * BK];
    int tid = threadIdx.x;
    int lane = tid & 63;
    int w = tid >> 6;
    int wm = w >> 1, wn = w & 1;
    int rowBase = blockIdx.y * BM;
    int colBase = blockIdx.x * BN;
    int lrow = lane >> 2;           // 0..15
    int lk = (lane & 3) * 8;        // 0,8,16,24

    f32x4 acc[4][4] = {};

    const int nk = K / BK;
    for (int kt = 0; kt < nk; ++kt) {
        int kBase = kt * BK;
#pragma unroll
        for (int i = 0; i < 2; ++i) {
            int r0 = w * 32 + i * 16;   // 16-row chunk per wave-instruction
            const u16* gA = A + (size_t)(rowBase + r0 + lrow) * K + kBase + lk;
            load16(gA, &As[r0 * BK]);
            const u16* gB = B + (size_t)(colBase + r0 + lrow) * K + kBase + lk;
            load16(gB, &Bs[r0 * BK]);
        }
        __syncthreads();
        bf16x8 af[4], bfr[4];
#pragma unroll
        for (int m = 0; m < 4; ++m)
            af[m] = *(const bf16x8*)&As[(wm * 64 + m * 16 + (lane & 15)) * BK + (lane >> 4) * 8];
#pragma unroll
        for (int n = 0; n < 4; ++n)
            bfr[n] = *(const bf16x8*)&Bs[(wn * 64 + n * 16 + (lane & 15)) * BK + (lane >> 4) * 8];
#pragma unroll
        for (int m = 0; m < 4; ++m)
#pragma unroll
            for (int n = 0; n < 4; ++n)
                acc[m][n] = __builtin_amdgcn_mfma_f32_16x16x32_bf16(af[m], bfr[n], acc[m][n], 0, 0, 0);
        __syncthreads();
    }

    int r0 = (lane >> 4) * 4;
    int cc = lane & 15;
#pragma unroll
    for (int m = 0; m < 4; ++m) {
#pragma unroll
        for (int n = 0; n < 4; ++n) {
            int row = rowBase + wm * 64 + m * 16 + r0;
            int col = colBase + wn * 64 + n * 16 + cc;
#pragma unroll
            for (int r = 0; r < 4; ++r) {
                size_t idx = (size_t)(row + r) * D + col;
                float v = acc[m][n][r];
                if (EPI == 0) {
                    ((u16*)Out)[idx] = f2b(v);
                } else if (EPI == 1) {
                    ((u16*)Out)[idx] = f2b(1.f / (1.f + __expf(-v)));
                } else if (EPI == 2) {
                    ((float*)Out)[idx] = v + Add[idx];
                } else if (EPI == 3) {
                    float rr = fmaxf(v, 0.f);
                    ((u16*)Out)[idx] = f2b(rr * rr);
                } else {
                    float s = 1.f / (1.f + __expf(-v));
                    ((float*)Out)[idx] = Add[idx] + s * b2f(Mul[idx]);
                }
            }
        }
    }
}

// ---------------- WKV recurrence (bf16 in/out) ----------------
__global__ __launch_bounds__(256) void wkv_kernel(
    const u16* __restrict__ k, const u16* __restrict__ v, const u16* __restrict__ sr,
    const float* __restrict__ td, const float* __restrict__ tf,
    u16* __restrict__ rwkv, int T) {
    const int C = 512;
    int gid = blockIdx.x * 256 + threadIdx.x;   // b_local*C + c
    int c = gid & (C - 1);
    int b = gid >> 9;
    float w = -__expf(td[c]);
    float u = tf[c];
    float aa = 0.f, bb = 0.f, pp = -1e38f;
    size_t idx = (size_t)b * T * C + c;
    for (int t = 0; t < T; ++t, idx += C) {
        float kt = b2f(k[idx]), vt = b2f(v[idx]);
        float ww = u + kt;
        float p = fmaxf(pp, ww);
        float e1 = __expf(pp - p), e2 = __expf(ww - p);
        float y = (e1 * aa + e2 * vt) / (e1 * bb + e2);
        float ww2 = pp + w;
        float p2 = fmaxf(ww2, kt);
        float e1b = __expf(ww2 - p2), e2b = __expf(kt - p2);
        aa = e1b * aa + e2b * vt;
        bb = e1b * bb + e2b;
        pp = p2;
        rwkv[idx] = f2b(b2f(sr[idx]) * y);
    }
}

extern "C" void kernel_launch(void* const* d_in, const int* in_sizes, int n_in,
                              void* d_out, int out_size, void* d_ws, size_t ws_size,
                              hipStream_t stream) {
    const int B = 512, T = 50, C = 512, H = 2048;
    const int NT = B * T;   // 25600

    const float* x     = (const float*)d_in[0];
    const float* ln1_g = (const float*)d_in[1];
    const float* ln1_b = (const float*)d_in[2];
    const float* ln2_g = (const float*)d_in[3];
    const float* ln2_b = (const float*)d_in[4];
    const float* amk   = (const float*)d_in[5];
    const float* amv   = (const float*)d_in[6];
    const float* amr   = (const float*)d_in[7];
    const float* td    = (const float*)d_in[8];
    const float* tf    = (const float*)d_in[9];
    const float* Wk    = (const float*)d_in[10];
    const float* Wv    = (const float*)d_in[11];
    const float* Wr    = (const float*)d_in[12];
    const float* Wo    = (const float*)d_in[13];
    const float* fmk   = (const float*)d_in[14];
    const float* fmr   = (const float*)d_in[15];
    const float* Fk    = (const float*)d_in[16];
    const float* Fv    = (const float*)d_in[17];
    const float* Fr    = (const float*)d_in[18];
    float* out = (float*)d_out;

    // ---- choose chunk rows R (multiple of T and 256) by ws_size ----
    const size_t WBYTES = ((size_t)C*C*2)*5 + ((size_t)H*C*2)*2 + 4096;
    int R = 6400;
    if (ws_size >= (size_t)25600 * 1024 * 7 + WBYTES)      R = 25600;
    else if (ws_size >= (size_t)12800 * 1024 * 7 + WBYTES) R = 12800;
    const int NCH = NT / R;

    char* ws = (char*)d_ws;
    size_t off = 0;
    auto alloc = [&](size_t bytes) {
        char* p = ws + off;
        off += (bytes + 255) & ~(size_t)255;
        return p;
    };
    const size_t uc = (size_t)R * C * 2;    // one bf16 unit [R][C]
    u16*   U0 = (u16*)alloc(uc);            // xk -> rwkv -> kk(lo)
    u16*   U1 = (u16*)alloc(uc);            // xv -> sr   -> kk(hi)
    u16*   U2 = (u16*)alloc(uc);            // xr -> kv
    u16*   U3 = (u16*)alloc(uc);            // k  -> fk
    u16*   U4 = (u16*)alloc(uc);            // v  -> fr
    float* X2 = (float*)alloc((size_t)R * C * 4);
    u16* bWk = (u16*)alloc((size_t)C * C * 2);
    u16* bWv = (u16*)alloc((size_t)C * C * 2);
    u16* bWr = (u16*)alloc((size_t)C * C * 2);
    u16* bWo = (u16*)alloc((size_t)C * C * 2);
    u16* bFk = (u16*)alloc((size_t)H * C * 2);
    u16* bFv = (u16*)alloc((size_t)C * H * 2);
    u16* bFr = (u16*)alloc((size_t)C * C * 2);
    u16* kk = U0;   // [R/2][H] bf16 == exactly U0+U1

    // weights -> bf16 (once)
    cvt_bf16<<<C * C / 1024, 256, 0, stream>>>(Wk, bWk, C * C);
    cvt_bf16<<<C * C / 1024, 256, 0, stream>>>(Wv, bWv, C * C);
    cvt_bf16<<<C * C / 1024, 256, 0, stream>>>(Wr, bWr, C * C);
    cvt_bf16<<<C * C / 1024, 256, 0, stream>>>(Wo, bWo, C * C);
    cvt_bf16<<<H * C / 1024, 256, 0, stream>>>(Fk, bFk, H * C);
    cvt_bf16<<<C * H / 1024, 256, 0, stream>>>(Fv, bFv, C * H);
    cvt_bf16<<<C * C / 1024, 256, 0, stream>>>(Fr, bFr, C * C);

    for (int ch = 0; ch < NCH; ++ch) {
        const float* xc  = x   + (size_t)ch * R * C;
        float*       oc  = out + (size_t)ch * R * C;
        dim3 g512(C / 128, R / 128);
        dim3 gH (H / 128, R / 256);         // kk GEMM: D=H cols, R/2 rows
        dim3 gKV(C / 128, R / 256);         // kv GEMM: D=C cols, R/2 rows  (was the bug)

        // attention branch
        ln_mix<3><<<R, 256, 0, stream>>>(xc, ln1_g, ln1_b, amk, amv, amr, U0, U1, U2, T);
        gemm_nt<0><<<g512, 256, 0, stream>>>(U0, bWk, U3, nullptr, nullptr, C, C);  // k
        gemm_nt<0><<<g512, 256, 0, stream>>>(U1, bWv, U4, nullptr, nullptr, C, C);  // v
        gemm_nt<1><<<g512, 256, 0, stream>>>(U2, bWr, U1, nullptr, nullptr, C, C);  // sr
        wkv_kernel<<<(R / T) * C / 256, 256, 0, stream>>>(U3, U4, U1, td, tf, U0, T);
        gemm_nt<2><<<g512, 256, 0, stream>>>(U0, bWo, X2, xc, nullptr, C, C);       // x2

        // FFN branch
        ln_mix<2><<<R, 256, 0, stream>>>(X2, ln2_g, ln2_b, fmk, nullptr, fmr, U3, nullptr, U4, T);
        for (int hhalf = 0; hhalf < 2; ++hhalf) {
            size_t ro = (size_t)hhalf * (R / 2);
            gemm_nt<3><<<gH,  256, 0, stream>>>(U3 + ro * C, bFk, kk, nullptr, nullptr, C, H);
            gemm_nt<0><<<gKV, 256, 0, stream>>>(kk, bFv, U2 + ro * C, nullptr, nullptr, H, C);
        }
        gemm_nt<4><<<g512, 256, 0, stream>>>(U4, bFr, oc, X2, U2, C, C);            // out
    }
}

// Round 5
// 540.887 us; speedup vs baseline: 1.1549x; 1.1549x over previous
//
#include <hip/hip_runtime.h>
#include <stdint.h>

typedef unsigned short u16;
typedef __bf16 bf16x8 __attribute__((ext_vector_type(8)));
typedef float f32x4 __attribute__((ext_vector_type(4)));

#define DEV static __device__ __forceinline__

DEV u16 f2b(float f) {                       // f32 -> bf16 RNE
    unsigned u = __float_as_uint(f);
    u += 0x7FFF + ((u >> 16) & 1);
    return (u16)(u >> 16);
}
DEV float b2f(u16 h) { return __uint_as_float((unsigned)h << 16); }

DEV void load16(const void* g, void* l) {    // async global->LDS, 16B/lane
    __builtin_amdgcn_global_load_lds((const __attribute__((address_space(1))) void*)g,
                                     (__attribute__((address_space(3))) void*)l, 16, 0, 0);
}

// ---------------- weight f32 -> bf16 ----------------
__global__ __launch_bounds__(256) void cvt_bf16(const float* __restrict__ src,
                                                u16* __restrict__ dst, int n) {
    int i = (blockIdx.x * 256 + threadIdx.x) * 4;
    if (i < n) {
        float4 f = *(const float4*)(src + i);
        ushort4 o;
        o.x = f2b(f.x); o.y = f2b(f.y); o.z = f2b(f.z); o.w = f2b(f.w);
        *(ushort4*)(dst + i) = o;
    }
}

// ---------------- fused LayerNorm + time-shift mix ----------------
template <int NOUT>
__global__ __launch_bounds__(256) void ln_mix(
    const float* __restrict__ x, const float* __restrict__ g, const float* __restrict__ be,
    const float* __restrict__ mk, const float* __restrict__ mv, const float* __restrict__ mr,
    u16* __restrict__ ok, u16* __restrict__ ov, u16* __restrict__ orr, int T) {
    const int C = 512;
    int row = blockIdx.x;
    int t = row % T;
    int tid = threadIdx.x;
    int c = tid * 2;
    const float* xt = x + (size_t)row * C;
    float2 vt = *(const float2*)(xt + c);
    float2 vp = make_float2(0.f, 0.f);
    if (t > 0) vp = *(const float2*)(xt - C + c);

    float s0 = vt.x + vt.y, s1 = vt.x * vt.x + vt.y * vt.y;
    float s2 = vp.x + vp.y, s3 = vp.x * vp.x + vp.y * vp.y;
#pragma unroll
    for (int off = 32; off; off >>= 1) {
        s0 += __shfl_down(s0, off); s1 += __shfl_down(s1, off);
        s2 += __shfl_down(s2, off); s3 += __shfl_down(s3, off);
    }
    __shared__ float sm[16];
    int w = tid >> 6;
    if ((tid & 63) == 0) { sm[w*4+0] = s0; sm[w*4+1] = s1; sm[w*4+2] = s2; sm[w*4+3] = s3; }
    __syncthreads();
    s0 = sm[0] + sm[4] + sm[8]  + sm[12];
    s1 = sm[1] + sm[5] + sm[9]  + sm[13];
    s2 = sm[2] + sm[6] + sm[10] + sm[14];
    s3 = sm[3] + sm[7] + sm[11] + sm[15];

    const float rC = 1.f / 512.f;
    float mu_t = s0 * rC, var_t = s1 * rC - mu_t * mu_t;
    float mu_p = s2 * rC, var_p = s3 * rC - mu_p * mu_p;
    float rs_t = rsqrtf(var_t + 1e-5f);
    float rs_p = rsqrtf(var_p + 1e-5f);

    float xk0[2], xv0[2], xr0[2];
#pragma unroll
    for (int j = 0; j < 2; ++j) {
        int cc = c + j;
        float gg = g[cc], bb = be[cc];
        float xv_ = (j ? vt.y : vt.x);
        float xp_ = (j ? vp.y : vp.x);
        float h  = (xv_ - mu_t) * rs_t * gg + bb;
        float hh = (t > 0) ? ((xp_ - mu_p) * rs_p * gg + bb) : 0.f;
        float a = mk[cc];
        xk0[j] = h * a + hh * (1.f - a);
        if (NOUT == 3) { float av = mv[cc]; xv0[j] = h * av + hh * (1.f - av); }
        float ar = mr[cc];
        xr0[j] = h * ar + hh * (1.f - ar);
    }
    size_t idx = (size_t)row * C + c;
    *(ushort2*)&ok[idx] = make_ushort2(f2b(xk0[0]), f2b(xk0[1]));
    if (NOUT == 3) *(ushort2*)&ov[idx] = make_ushort2(f2b(xv0[0]), f2b(xv0[1]));
    *(ushort2*)&orr[idx] = make_ushort2(f2b(xr0[0]), f2b(xr0[1]));
}

// ---------------- NT GEMM: out[n,d] = sum_c A[n,c]*B[d,c] ----------------
// BM=64, BK=64, BN template {64,128}. 4 waves as 2x2, each 32 x BN/2.
// LDS XOR-swizzle: LDS[row][g] = G[row][g ^ (row&7)] via pre-swizzled global src.
// XCD-chunked block swizzle for L2 locality (nwg must be %8==0).
// EPI: 0 bf16 raw | 2 f32 v+Add | 3 bf16 relu^2 | 4 f32 Add+sig(v)*Mul
//      5 kvr mode: z<2 bf16 raw, z==2 bf16 sigmoid
template <int BN, int EPI>
__global__ __launch_bounds__(256) void gemm64(
    const u16* __restrict__ A0, int strideAz,
    const u16* __restrict__ B0, int strideBz,
    void* O0, void* O1, void* O2,
    const float* __restrict__ Add, const u16* __restrict__ Mul,
    int K, int D) {
    const int BM = 64, BK = 64;
    const int NT_ = BN / 32;                 // n-tiles per wave
    __shared__ __align__(16) u16 As[BM * BK];
    __shared__ __align__(16) u16 Bs[BN * BK];

    // XCD-aware swizzle: contiguous logical span per XCD, x fastest (A reuse)
    int gx = gridDim.x, gy = gridDim.y;
    int fid = blockIdx.x + gx * (blockIdx.y + gy * blockIdx.z);
    int nwg = gx * gy * gridDim.z;
    int swz = (fid & 7) * (nwg >> 3) + (fid >> 3);
    int bx = swz % gx;
    int tmp = swz / gx;
    int by = tmp % gy;
    int bz = tmp / gy;

    const u16* A = A0 + (size_t)bz * strideAz;
    const u16* B = B0 + (size_t)bz * strideBz;
    void* Out = (bz == 0) ? O0 : (bz == 1) ? O1 : O2;

    int tid = threadIdx.x;
    int lane = tid & 63;
    int w = tid >> 6;
    int wm = w >> 1, wn = w & 1;
    int rowBase = by * BM;
    int colBase = bx * BN;
    int l8 = lane >> 3;                       // row within 8-row staging chunk
    int gsrc = ((lane & 7) ^ l8) * 8;         // pre-swizzled source granule (elems)

    f32x4 acc[2][NT_] = {};

    for (int kt = 0; kt < K; kt += BK) {
#pragma unroll
        for (int i = 0; i < 2; ++i) {         // A: 64 rows, 8 rows/instr, 2/wave
            int r0 = w * 16 + i * 8;
            load16(A + (size_t)(rowBase + r0 + l8) * K + kt + gsrc, &As[r0 * BK]);
        }
#pragma unroll
        for (int i = 0; i < BN / 32; ++i) {   // B: BN rows
            int r0 = w * (BN / 4) + i * 8;
            load16(B + (size_t)(colBase + r0 + l8) * K + kt + gsrc, &Bs[r0 * BK]);
        }
        __syncthreads();

        bf16x8 af[2][2], bfr[NT_][2];
#pragma unroll
        for (int m = 0; m < 2; ++m) {
            int row = wm * 32 + m * 16 + (lane & 15);
            int rx = row & 7;
#pragma unroll
            for (int s = 0; s < 2; ++s) {
                int gsw = (s * 4 + (lane >> 4)) ^ rx;
                af[m][s] = *(const bf16x8*)&As[row * BK + gsw * 8];
            }
        }
#pragma unroll
        for (int n = 0; n < NT_; ++n) {
            int col = wn * (BN / 2) + n * 16 + (lane & 15);
            int rx = col & 7;
#pragma unroll
            for (int s = 0; s < 2; ++s) {
                int gsw = (s * 4 + (lane >> 4)) ^ rx;
                bfr[n][s] = *(const bf16x8*)&Bs[col * BK + gsw * 8];
            }
        }
#pragma unroll
        for (int s = 0; s < 2; ++s)
#pragma unroll
            for (int m = 0; m < 2; ++m)
#pragma unroll
                for (int n = 0; n < NT_; ++n)
                    acc[m][n] = __builtin_amdgcn_mfma_f32_16x16x32_bf16(af[m][s], bfr[n][s], acc[m][n], 0, 0, 0);
        __syncthreads();
    }

    int r0e = (lane >> 4) * 4;
    int ce = lane & 15;
#pragma unroll
    for (int m = 0; m < 2; ++m) {
#pragma unroll
        for (int n = 0; n < NT_; ++n) {
            int row = rowBase + wm * 32 + m * 16 + r0e;
            int col = colBase + wn * (BN / 2) + n * 16 + ce;
#pragma unroll
            for (int r = 0; r < 4; ++r) {
                size_t idx = (size_t)(row + r) * D + col;
                float v = acc[m][n][r];
                if (EPI == 0) {
                    ((u16*)Out)[idx] = f2b(v);
                } else if (EPI == 2) {
                    ((float*)Out)[idx] = v + Add[idx];
                } else if (EPI == 3) {
                    float rr = fmaxf(v, 0.f);
                    ((u16*)Out)[idx] = f2b(rr * rr);
                } else if (EPI == 4) {
                    float s = 1.f / (1.f + __expf(-v));
                    ((float*)Out)[idx] = Add[idx] + s * b2f(Mul[idx]);
                } else {                      // EPI 5: kvr
                    ((u16*)Out)[idx] = (bz == 2) ? f2b(1.f / (1.f + __expf(-v))) : f2b(v);
                }
            }
        }
    }
}

// ---------------- WKV recurrence (bf16 in/out) ----------------
__global__ __launch_bounds__(256) void wkv_kernel(
    const u16* __restrict__ k, const u16* __restrict__ v, const u16* __restrict__ sr,
    const float* __restrict__ td, const float* __restrict__ tf,
    u16* __restrict__ rwkv, int T) {
    const int C = 512;
    int gid = blockIdx.x * 256 + threadIdx.x;
    int c = gid & (C - 1);
    int b = gid >> 9;
    float w = -__expf(td[c]);
    float u = tf[c];
    float aa = 0.f, bb = 0.f, pp = -1e38f;
    size_t idx = (size_t)b * T * C + c;
    for (int t = 0; t < T; ++t, idx += C) {
        float kt = b2f(k[idx]), vt = b2f(v[idx]);
        float ww = u + kt;
        float p = fmaxf(pp, ww);
        float e1 = __expf(pp - p), e2 = __expf(ww - p);
        float y = (e1 * aa + e2 * vt) / (e1 * bb + e2);
        float ww2 = pp + w;
        float p2 = fmaxf(ww2, kt);
        float e1b = __expf(ww2 - p2), e2b = __expf(kt - p2);
        aa = e1b * aa + e2b * vt;
        bb = e1b * bb + e2b;
        pp = p2;
        rwkv[idx] = f2b(b2f(sr[idx]) * y);
    }
}

extern "C" void kernel_launch(void* const* d_in, const int* in_sizes, int n_in,
                              void* d_out, int out_size, void* d_ws, size_t ws_size,
                              hipStream_t stream) {
    const int B = 512, T = 50, C = 512, H = 2048;
    const int NT = B * T;   // 25600

    const float* x     = (const float*)d_in[0];
    const float* ln1_g = (const float*)d_in[1];
    const float* ln1_b = (const float*)d_in[2];
    const float* ln2_g = (const float*)d_in[3];
    const float* ln2_b = (const float*)d_in[4];
    const float* amk   = (const float*)d_in[5];
    const float* amv   = (const float*)d_in[6];
    const float* amr   = (const float*)d_in[7];
    const float* td    = (const float*)d_in[8];
    const float* tf    = (const float*)d_in[9];
    const float* Wk    = (const float*)d_in[10];
    const float* Wv    = (const float*)d_in[11];
    const float* Wr    = (const float*)d_in[12];
    const float* Wo    = (const float*)d_in[13];
    const float* fmk   = (const float*)d_in[14];
    const float* fmr   = (const float*)d_in[15];
    const float* Fk    = (const float*)d_in[16];
    const float* Fv    = (const float*)d_in[17];
    const float* Fr    = (const float*)d_in[18];
    float* out = (float*)d_out;

    // ---- chunk rows R (must divide 25600; multiple of lcm(50,256)=6400) ----
    const size_t WBYTES = ((size_t)C*C*2)*6 + ((size_t)H*C*2)*2 + 4096;
    int R = 6400;
    if (ws_size >= (size_t)25600 * 1024 * 7 + WBYTES)      R = 25600;
    else if (ws_size >= (size_t)12800 * 1024 * 7 + WBYTES) R = 12800;
    const int NCH = NT / R;

    char* ws = (char*)d_ws;
    size_t off = 0;
    auto alloc = [&](size_t bytes) {
        char* p = ws + off;
        off += (bytes + 255) & ~(size_t)255;
        return p;
    };
    const size_t uc = (size_t)R * C * 2;    // one bf16 unit [R][C]
    u16*   U0 = (u16*)alloc(uc);            // xk -> rwkv -> kk(2 units w/ U1)
    u16*   U1 = (u16*)alloc(uc);            // xv
    u16*   U2 = (u16*)alloc(uc);            // xr -> kv
    u16*   U3 = (u16*)alloc(uc);            // k  -> fk
    u16*   U4 = (u16*)alloc(uc);            // v  -> fr
    float* X2 = (float*)alloc((size_t)R * C * 4);   // first half doubles as sr (U5)
    u16*   U5 = (u16*)X2;                   // sr (dead before X2 written)
    u16* bWkvr = (u16*)alloc((size_t)3 * C * C * 2);
    u16* bWo   = (u16*)alloc((size_t)C * C * 2);
    u16* bFk   = (u16*)alloc((size_t)H * C * 2);
    u16* bFv   = (u16*)alloc((size_t)C * H * 2);
    u16* bFr   = (u16*)alloc((size_t)C * C * 2);
    u16* kk = U0;   // [R/2][H] bf16 == exactly U0+U1 (contiguous)

    // weights -> bf16 (once)
    cvt_bf16<<<C * C / 1024, 256, 0, stream>>>(Wk, bWkvr,             C * C);
    cvt_bf16<<<C * C / 1024, 256, 0, stream>>>(Wv, bWkvr + C * C,     C * C);
    cvt_bf16<<<C * C / 1024, 256, 0, stream>>>(Wr, bWkvr + 2 * C * C, C * C);
    cvt_bf16<<<C * C / 1024, 256, 0, stream>>>(Wo, bWo, C * C);
    cvt_bf16<<<H * C / 1024, 256, 0, stream>>>(Fk, bFk, H * C);
    cvt_bf16<<<C * H / 1024, 256, 0, stream>>>(Fv, bFv, C * H);
    cvt_bf16<<<C * C / 1024, 256, 0, stream>>>(Fr, bFr, C * C);

    for (int ch = 0; ch < NCH; ++ch) {
        const float* xc  = x   + (size_t)ch * R * C;
        float*       oc  = out + (size_t)ch * R * C;

        // ---- attention branch ----
        ln_mix<3><<<R, 256, 0, stream>>>(xc, ln1_g, ln1_b, amk, amv, amr, U0, U1, U2, T);
        // k,v,sr in one z-batched dispatch: grid (4, R/64, 3)
        gemm64<128, 5><<<dim3(C / 128, R / 64, 3), 256, 0, stream>>>(
            U0, R * C, bWkvr, C * C, U3, U4, U5, nullptr, nullptr, C, C);
        wkv_kernel<<<(R / T) * C / 256, 256, 0, stream>>>(U3, U4, U5, td, tf, U0, T);
        gemm64<128, 2><<<dim3(C / 128, R / 64, 1), 256, 0, stream>>>(
            U0, 0, bWo, 0, X2, nullptr, nullptr, xc, nullptr, C, C);

        // ---- FFN branch ----
        ln_mix<2><<<R, 256, 0, stream>>>(X2, ln2_g, ln2_b, fmk, nullptr, fmr, U3, nullptr, U4, T);
        for (int hh = 0; hh < 2; ++hh) {
            size_t ro = (size_t)hh * (R / 2);
            gemm64<128, 3><<<dim3(H / 128, R / 128, 1), 256, 0, stream>>>(
                U3 + ro * C, 0, bFk, 0, kk, nullptr, nullptr, nullptr, nullptr, C, H);
            gemm64<64, 0><<<dim3(C / 64, R / 128, 1), 256, 0, stream>>>(
                kk, 0, bFv, 0, U2 + ro * C, nullptr, nullptr, nullptr, nullptr, H, C);
        }
        gemm64<128, 4><<<dim3(C / 128, R / 64, 1), 256, 0, stream>>>(
            U4, 0, bFr, 0, oc, nullptr, nullptr, X2, U2, C, C);
    }
}